// Round 4
// baseline (83.885 us; speedup 1.0000x reference)
//
#include <hip/hip_runtime.h>
#include <math.h>

#define T_LEN 8192
#define EPSF  1e-6f

typedef __attribute__((ext_vector_type(8))) short short8;
typedef __attribute__((ext_vector_type(4))) float float4v;

// ---------------------------------------------------------------------------
// Single fused kernel. One block = (batch b, 256-row t-strip), 1024 blocks x
// 256 threads, __launch_bounds__(256,4): 4 blocks/CU, one residency round.
//
// R4 change (isolated): B fragments are NO LONGER held in 64 persistent VGPRs
// across phase 2 (suspected spill/pressure source under the forced 128-VGPR
// cap). They live in a fragment-linear LDS layout Bfrag[pt*2+h][lane]
// (stride-1 lane-contiguous b128 reads, conflict-free) and are re-read per
// (u, pt) use; an asm launder on the index stops LICM from re-hoisting them
// into registers. Peak live VGPRs ~120 -> ~85. All arithmetic, MFMA order,
// epilogue, stores, and barrier structure are byte-identical to R3.
//
// Phase 0/1 (one barrier): threads 0-63: shapelet global->reg, EXACT serial
//   two-pass znorm + bf16 hi/lo split, written to Bfrag layout + lsum/ls2.
//   threads 64-143: stage x window (80 float4 -> xs[320]).
// Phase 1.5: window stats, one row per thread, verbatim math, packed float4
//   {mu,inv,w2} -> lstat. sm4/sv4 -> registers. barrier.
// Phase 2: per u (four 64-row units): A-pack from xs; per pt: 4 laundered
//   b128 B reads + 3-MFMA bf16 hi/lo GEMM (same order); epilogue folds
//   window znorm + exp, float4 stores. Rows t<32 / t>8160 zero-padded.
// LDS: Bfrag 16 KB + xs 1.25 KB + lstat 4 KB + lsum/ls2 0.5 KB ~= 21.8 KB.
// ---------------------------------------------------------------------------
__global__ __launch_bounds__(256, 4) void shapelet_fused(
        const float* __restrict__ x,
        const float* __restrict__ sh,
        float* __restrict__ out) {
    __shared__ short8 BfragH[8][64];           // 8 KB: [pt*2+h][lane] hi frags
    __shared__ short8 BfragL[8][64];           // 8 KB: lo frags
    __shared__ __align__(16) float xs[320];    // x[t0-32 .. t0+287]
    __shared__ float4 lstat[256];              // {mu, inv, w2, -} per row
    __shared__ __align__(16) float lsum[64];   // logical-p order
    __shared__ __align__(16) float ls2[64];

    const int tid  = threadIdx.x;
    const int lane = tid & 63;
    const int wave = tid >> 6;
    const int n    = lane & 15;
    const int quad = lane >> 4;

    const int super = blockIdx.x & 31;         // 32 strips of 256 rows
    const int b     = blockIdx.x >> 5;         // 32 batches
    const int t0    = super << 8;

    // ---------------- phase 0/1: prep (global->reg) + xs staging ----------
    if (tid < 64) {
        const int p = tid;
        const int pt_p = p & 3;
        const int n_p  = p >> 2;

        // load shapelet p into registers (16 x dwordx4)
        float S[64];
        const float4* s4 = (const float4*)(sh + (size_t)p * 64);
#pragma unroll
        for (int i = 0; i < 16; ++i) {
            float4 v = s4[i];
            S[4 * i + 0] = v.x;
            S[4 * i + 1] = v.y;
            S[4 * i + 2] = v.z;
            S[4 * i + 3] = v.w;
        }

        // EXACT prior-round prep arithmetic (same order, same ops).
        float s1 = 0.f;
#pragma unroll
        for (int l = 0; l < 64; ++l) s1 += S[l];
        float mu = s1 * (1.f / 64.f);
        float sq = 0.f;
#pragma unroll
        for (int l = 0; l < 64; ++l) { float d = S[l] - mu; sq = fmaf(d, d, sq); }
        float sd  = fmaxf(sqrtf(sq * (1.f / 64.f)), EPSF);
        float inv = 1.f / sd;
        float ssum = 0.f, ss2 = 0.f;

        unsigned* BH = (unsigned*)BfragH;
        unsigned* BL = (unsigned*)BfragL;
#pragma unroll
        for (int l2 = 0; l2 < 32; ++l2) {
            const int k = 2 * l2;
            unsigned pk_h, pk_l;
            {   // element k (low half)
                float v = S[k];
                float s = (v - mu) * inv;
                unsigned ub = __float_as_uint(s);
                float hi = __uint_as_float(ub & 0xFFFF0000u);
                float lo = s - hi;
                unsigned lb = __float_as_uint(lo) & 0xFFFF0000u;
                pk_h = ub >> 16;
                pk_l = lb >> 16;
                float eff = hi + __uint_as_float(lb);
                ssum += eff;
                ss2  = fmaf(eff, eff, ss2);
            }
            {   // element k+1 (high half)
                float v = S[k + 1];
                float s = (v - mu) * inv;
                unsigned ub = __float_as_uint(s);
                float hi = __uint_as_float(ub & 0xFFFF0000u);
                float lo = s - hi;
                unsigned lb = __float_as_uint(lo) & 0xFFFF0000u;
                pk_h |= (ub & 0xFFFF0000u);
                pk_l |= lb;
                float eff = hi + __uint_as_float(lb);
                ssum += eff;
                ss2  = fmaf(eff, eff, ss2);
            }
            // fragment-linear address: frag f = pt*2 + (k>>5),
            // lane = ((k>>3)&3)*16 + n_p, dword j = (k&7)>>1
            const int f  = (pt_p << 1) + (k >> 5);
            const int li = (((k >> 3) & 3) << 4) + n_p;
            const int di = (((f << 6) + li) << 2) + ((k & 7) >> 1);
            BH[di] = pk_h;
            BL[di] = pk_l;
        }
        lsum[p] = ssum;
        ls2[p]  = ss2;
    } else if (tid < 144) {
        // stage x window into LDS (80 float4 = 320 floats)
        const int i = tid - 64;
        int g0 = t0 - 32 + (i << 2);
        float4 v;
        if (g0 >= 0 && g0 + 3 < T_LEN) {
            v = *(const float4*)(x + (size_t)b * T_LEN + g0);
        } else {
            float* vp = (float*)&v;
#pragma unroll
            for (int e = 0; e < 4; ++e) {
                int g = g0 + e;
                vp[e] = ((unsigned)g < (unsigned)T_LEN) ? x[(size_t)b * T_LEN + g] : 0.f;
            }
        }
        *(float4*)&xs[i << 2] = v;
    }
    __syncthreads();

    // ---------------- phase 1.5: window stats + stat loads -----------------
    {
        const int r = tid;
        float s1 = 0.f, sq = 0.f;
#pragma unroll
        for (int l = 0; l < 64; ++l) {
            float v = xs[r + l];
            s1 += v; sq = fmaf(v, v, sq);
        }
        float mu  = s1 * (1.f / 64.f);
        float var = fmaxf(sq * (1.f / 64.f) - mu * mu, 0.f);
        float sd  = fmaxf(sqrtf(var), EPSF);
        float inv = 1.f / sd;
        float4 st;
        st.x = mu;
        st.y = inv;
        st.z = 64.f * var * inv * inv;
        st.w = 0.f;
        lstat[r] = st;
    }
    const float4 sm4 = *(const float4*)&lsum[n << 2];   // logical 4n..4n+3
    const float4 sv4 = *(const float4*)&ls2[n << 2];
    __syncthreads();

    // ---------------- phase 2: MFMA main -----------------------------------
    const short8* BH8 = (const short8*)BfragH;
    const short8* BL8 = (const short8*)BfragL;

#pragma unroll
    for (int u = 0; u < 4; ++u) {
        // A fragments: A[m][k] = xs[u*64 + wave*16 + m + k]  (verbatim)
        const int abase = (u << 6) + (wave << 4) + n + (quad << 3);
        short8 Ah[2], Al[2];
#pragma unroll
        for (int h = 0; h < 2; ++h) {
#pragma unroll
            for (int j = 0; j < 8; ++j) {
                float v = xs[abase + h * 32 + j];
                unsigned ub = __float_as_uint(v);
                unsigned hb = ub & 0xFFFF0000u;
                float lo = v - __uint_as_float(hb);
                Ah[h][j] = (short)(ub >> 16);
                Al[h][j] = (short)(__float_as_uint(lo) >> 16);
            }
        }

        float4v acc[4];
#pragma unroll
        for (int pt = 0; pt < 4; ++pt) {
            // per-use B reads, laundered so LICM can't hoist them into
            // persistent VGPRs across the u loop.
            unsigned off = ((unsigned)(pt << 1) << 6) + (unsigned)lane;
            asm volatile("" : "+v"(off));
            short8 bh0 = BH8[off];
            short8 bh1 = BH8[off + 64];
            short8 bl0 = BL8[off];
            short8 bl1 = BL8[off + 64];

            float4v a = {0.f, 0.f, 0.f, 0.f};
            // h = 0 (same accumulation order as all prior rounds)
            a = __builtin_amdgcn_mfma_f32_16x16x32_bf16(Ah[0], bh0, a, 0, 0, 0);
            a = __builtin_amdgcn_mfma_f32_16x16x32_bf16(Ah[0], bl0, a, 0, 0, 0);
            a = __builtin_amdgcn_mfma_f32_16x16x32_bf16(Al[0], bh0, a, 0, 0, 0);
            // h = 1
            a = __builtin_amdgcn_mfma_f32_16x16x32_bf16(Ah[1], bh1, a, 0, 0, 0);
            a = __builtin_amdgcn_mfma_f32_16x16x32_bf16(Ah[1], bl1, a, 0, 0, 0);
            a = __builtin_amdgcn_mfma_f32_16x16x32_bf16(Al[1], bh1, a, 0, 0, 0);
            acc[pt] = a;
        }

        // epilogue: fold window znorm + exp, float4 store at cols 4n..4n+3
#pragma unroll
        for (int r = 0; r < 4; ++r) {
            // C/D layout: col = lane&15, row = quad*4 + r
            int tl = (u << 6) + (wave << 4) + (quad << 2) + r;
            int tg = t0 + tl;
            bool valid = (tg >= 32) && (tg <= 8160);
            float4 st = lstat[tl];
            float mu  = st.x;
            float inv = st.y;
            float w2  = st.z;
            float d0 = (acc[0][r] - mu * sm4.x) * inv;
            float d1 = (acc[1][r] - mu * sm4.y) * inv;
            float d2 = (acc[2][r] - mu * sm4.z) * inv;
            float d3 = (acc[3][r] - mu * sm4.w) * inv;
            float4 o;
            o.x = valid ? __expf(-(w2 + sv4.x - 2.f * d0)) : 0.f;
            o.y = valid ? __expf(-(w2 + sv4.y - 2.f * d1)) : 0.f;
            o.z = valid ? __expf(-(w2 + sv4.z - 2.f * d2)) : 0.f;
            o.w = valid ? __expf(-(w2 + sv4.w - 2.f * d3)) : 0.f;
            *(float4*)(out + (((size_t)(b * T_LEN + tg)) << 6) + (n << 2)) = o;
        }
    }
}

extern "C" void kernel_launch(void* const* d_in, const int* in_sizes, int n_in,
                              void* d_out, int out_size, void* d_ws, size_t ws_size,
                              hipStream_t stream) {
    const float* x  = (const float*)d_in[0];   // (32, 8192, 1)
    const float* sh = (const float*)d_in[1];   // (64, 1, 64)
    float* out = (float*)d_out;                // (32, 8192, 64)

    shapelet_fused<<<32 * 32, 256, 0, stream>>>(x, sh, out);
}

// Round 5
// 82.990 us; speedup vs baseline: 1.0108x; 1.0108x over previous
//
#include <hip/hip_runtime.h>
#include <math.h>

#define T_LEN 8192
#define EPSF  1e-6f

typedef __attribute__((ext_vector_type(8))) short short8;
typedef __attribute__((ext_vector_type(4))) float float4v;

// ---------------------------------------------------------------------------
// Single fused kernel. One block = (batch b, 256-row t-strip), 1024 blocks x
// 256 threads, __launch_bounds__(256,4): 4 blocks/CU, one residency round.
//
// R5 changes (vs R3, which matched the 82.9us baseline):
//  (a) STAGGERED unit order: wave w of block g runs the four 64-row units in
//      order u = (uu + w + g) & 3. Phase 2 has no barriers, outputs are
//      disjoint, xs/lstat are read-only => pure reordering, zero arithmetic
//      change. Purpose: break CU-wide phase lockstep (all 16 resident waves
//      doing LDS-bound A-pack at the same instant, then all store-bursting
//      at the same instant) so LDS / VALU / store pipes overlap instead of
//      time-slicing. Pipe-sum model: serialized ~24us+gaps vs overlapped
//      ~12-14us per CU.
//  (b) Pair-packed A-prep: one v_perm_b32 yields the bf16-hi pair of two
//      consecutive window floats (same bit trick verified in R1 phase-1.5),
//      one more for the lo pair. Element arithmetic bit-identical
//      (hi = ub>>16 ; lo = float(v - as_float(ub&0xFFFF0000)) >> 16).
//
// Phase 0/1 (one barrier): threads 0-63: shapelet global->reg, EXACT serial
//   two-pass znorm + bf16 hi/lo split -> LDS Bhi/Blo (permuted row
//   c = (p&3)*16 + p>>2) + lsum/ls2. threads 64-143: stage x window -> xs.
// Phase 1.5: window stats, one row per thread, verbatim math, float4 pack
//   {mu,inv,w2} -> lstat; B fragments + stats -> registers. barrier.
// Phase 2: per unit (staggered): pair-pack A from xs; 3-MFMA bf16 hi/lo
//   GEMM per pt (verbatim order); epilogue folds window znorm + exp,
//   float4 stores. Rows t<32 / t>8160 are the reference zero padding.
// ---------------------------------------------------------------------------
__global__ __launch_bounds__(256, 4) void shapelet_fused(
        const float* __restrict__ x,
        const float* __restrict__ sh,
        float* __restrict__ out) {
    __shared__ unsigned short Bhi[64][72];     // 9 KB, 144 B rows (16B-aligned)
    __shared__ unsigned short Blo[64][72];     // 9 KB
    __shared__ __align__(16) float xs[320];    // x[t0-32 .. t0+287]
    __shared__ float4 lstat[256];              // {mu, inv, w2, -} per row
    __shared__ __align__(16) float lsum[64];   // logical-p order
    __shared__ __align__(16) float ls2[64];

    const int tid  = threadIdx.x;
    const int lane = tid & 63;
    const int wave = tid >> 6;
    const int n    = lane & 15;
    const int quad = lane >> 4;

    const int super = blockIdx.x & 31;         // 32 strips of 256 rows
    const int b     = blockIdx.x >> 5;         // 32 batches
    const int t0    = super << 8;

    // ---------------- phase 0/1: prep (global->reg) + xs staging ----------
    if (tid < 64) {
        const int p = tid;
        const int c = ((p & 3) << 4) + (p >> 2);   // permuted B row

        float S[64];
        const float4* s4 = (const float4*)(sh + (size_t)p * 64);
#pragma unroll
        for (int i = 0; i < 16; ++i) {
            float4 v = s4[i];
            S[4 * i + 0] = v.x;
            S[4 * i + 1] = v.y;
            S[4 * i + 2] = v.z;
            S[4 * i + 3] = v.w;
        }

        // EXACT prior-round prep arithmetic (same order, same ops).
        float s1 = 0.f;
#pragma unroll
        for (int l = 0; l < 64; ++l) s1 += S[l];
        float mu = s1 * (1.f / 64.f);
        float sq = 0.f;
#pragma unroll
        for (int l = 0; l < 64; ++l) { float d = S[l] - mu; sq = fmaf(d, d, sq); }
        float sd  = fmaxf(sqrtf(sq * (1.f / 64.f)), EPSF);
        float inv = 1.f / sd;
        float ssum = 0.f, ss2 = 0.f;
#pragma unroll
        for (int l2 = 0; l2 < 32; ++l2) {
            unsigned pk_h, pk_l;
            {   // element 2*l2 (low half)
                float v = S[2 * l2];
                float s = (v - mu) * inv;
                unsigned ub = __float_as_uint(s);
                float hi = __uint_as_float(ub & 0xFFFF0000u);
                float lo = s - hi;
                unsigned lb = __float_as_uint(lo) & 0xFFFF0000u;
                pk_h = ub >> 16;
                pk_l = lb >> 16;
                float eff = hi + __uint_as_float(lb);
                ssum += eff;
                ss2  = fmaf(eff, eff, ss2);
            }
            {   // element 2*l2+1 (high half)
                float v = S[2 * l2 + 1];
                float s = (v - mu) * inv;
                unsigned ub = __float_as_uint(s);
                float hi = __uint_as_float(ub & 0xFFFF0000u);
                float lo = s - hi;
                unsigned lb = __float_as_uint(lo) & 0xFFFF0000u;
                pk_h |= (ub & 0xFFFF0000u);
                pk_l |= lb;
                float eff = hi + __uint_as_float(lb);
                ssum += eff;
                ss2  = fmaf(eff, eff, ss2);
            }
            *(unsigned*)&Bhi[c][2 * l2] = pk_h;
            *(unsigned*)&Blo[c][2 * l2] = pk_l;
        }
        lsum[p] = ssum;
        ls2[p]  = ss2;
    } else if (tid < 144) {
        // stage x window into LDS (80 float4 = 320 floats)
        const int i = tid - 64;
        int g0 = t0 - 32 + (i << 2);
        float4 v;
        if (g0 >= 0 && g0 + 3 < T_LEN) {
            v = *(const float4*)(x + (size_t)b * T_LEN + g0);
        } else {
            float* vp = (float*)&v;
#pragma unroll
            for (int e = 0; e < 4; ++e) {
                int g = g0 + e;
                vp[e] = ((unsigned)g < (unsigned)T_LEN) ? x[(size_t)b * T_LEN + g] : 0.f;
            }
        }
        *(float4*)&xs[i << 2] = v;
    }
    __syncthreads();

    // ---------------- phase 1.5: window stats + fragment loads -------------
    {
        const int r = tid;
        float s1 = 0.f, sq = 0.f;
#pragma unroll
        for (int l = 0; l < 64; ++l) {
            float v = xs[r + l];
            s1 += v; sq = fmaf(v, v, sq);
        }
        float mu  = s1 * (1.f / 64.f);
        float var = fmaxf(sq * (1.f / 64.f) - mu * mu, 0.f);
        float sd  = fmaxf(sqrtf(var), EPSF);
        float inv = 1.f / sd;
        float4 st;
        st.x = mu;
        st.y = inv;
        st.z = 64.f * var * inv * inv;
        st.w = 0.f;
        lstat[r] = st;
    }

    // B fragments -> registers (layout identical to proven kernel):
    // lane holds B[k = quad*8+j + 32*h][col = lane&15]; permuted row
    // c = pt*16+n is logical shapelet 4n+pt.
    short8 Bh[4][2], Bl[4][2];
#pragma unroll
    for (int pt = 0; pt < 4; ++pt)
#pragma unroll
        for (int h = 0; h < 2; ++h) {
            Bh[pt][h] = *(const short8*)&Bhi[pt * 16 + n][h * 32 + (quad << 3)];
            Bl[pt][h] = *(const short8*)&Blo[pt * 16 + n][h * 32 + (quad << 3)];
        }
    const float4 sm4 = *(const float4*)&lsum[n << 2];   // logical 4n..4n+3
    const float4 sv4 = *(const float4*)&ls2[n << 2];
    __syncthreads();

    // ---------------- phase 2: MFMA main (staggered unit order) ------------
    const int stag = (wave + (int)blockIdx.x) & 3;

#pragma unroll
    for (int uu = 0; uu < 4; ++uu) {
        const int u = (uu + stag) & 3;

        // A fragments: A[m][k] = xs[u*64 + wave*16 + m + k]; pair-packed.
        const int abase = (u << 6) + (wave << 4) + n + (quad << 3);
        short8 Ah[2], Al[2];
#pragma unroll
        for (int h = 0; h < 2; ++h) {
            union { unsigned w[4]; short8 v; } ph, pl;
#pragma unroll
            for (int j2 = 0; j2 < 4; ++j2) {
                float v0 = xs[abase + h * 32 + 2 * j2];
                float v1 = xs[abase + h * 32 + 2 * j2 + 1];
                unsigned u0 = __float_as_uint(v0);
                unsigned u1 = __float_as_uint(v1);
                float l0 = v0 - __uint_as_float(u0 & 0xFFFF0000u);
                float l1 = v1 - __uint_as_float(u1 & 0xFFFF0000u);
                // dst = { u1.hi16 : u0.hi16 }  (low short = element 2*j2)
                ph.w[j2] = __builtin_amdgcn_perm(u1, u0, 0x07060302u);
                pl.w[j2] = __builtin_amdgcn_perm(__float_as_uint(l1),
                                                 __float_as_uint(l0), 0x07060302u);
            }
            Ah[h] = ph.v;
            Al[h] = pl.v;
        }

        float4v acc[4];
#pragma unroll
        for (int pt = 0; pt < 4; ++pt) {
            float4v a = {0.f, 0.f, 0.f, 0.f};
#pragma unroll
            for (int h = 0; h < 2; ++h) {
                a = __builtin_amdgcn_mfma_f32_16x16x32_bf16(Ah[h], Bh[pt][h], a, 0, 0, 0);
                a = __builtin_amdgcn_mfma_f32_16x16x32_bf16(Ah[h], Bl[pt][h], a, 0, 0, 0);
                a = __builtin_amdgcn_mfma_f32_16x16x32_bf16(Al[h], Bh[pt][h], a, 0, 0, 0);
            }
            acc[pt] = a;
        }

        // epilogue: fold window znorm + exp, float4 store at cols 4n..4n+3
#pragma unroll
        for (int r = 0; r < 4; ++r) {
            // C/D layout: col = lane&15, row = quad*4 + r
            int tl = (u << 6) + (wave << 4) + (quad << 2) + r;
            int tg = t0 + tl;
            bool valid = (tg >= 32) && (tg <= 8160);
            float4 st = lstat[tl];
            float mu  = st.x;
            float inv = st.y;
            float w2  = st.z;
            float d0 = (acc[0][r] - mu * sm4.x) * inv;
            float d1 = (acc[1][r] - mu * sm4.y) * inv;
            float d2 = (acc[2][r] - mu * sm4.z) * inv;
            float d3 = (acc[3][r] - mu * sm4.w) * inv;
            float4 o;
            o.x = valid ? __expf(-(w2 + sv4.x - 2.f * d0)) : 0.f;
            o.y = valid ? __expf(-(w2 + sv4.y - 2.f * d1)) : 0.f;
            o.z = valid ? __expf(-(w2 + sv4.z - 2.f * d2)) : 0.f;
            o.w = valid ? __expf(-(w2 + sv4.w - 2.f * d3)) : 0.f;
            *(float4*)(out + (((size_t)(b * T_LEN + tg)) << 6) + (n << 2)) = o;
        }
    }
}

extern "C" void kernel_launch(void* const* d_in, const int* in_sizes, int n_in,
                              void* d_out, int out_size, void* d_ws, size_t ws_size,
                              hipStream_t stream) {
    const float* x  = (const float*)d_in[0];   // (32, 8192, 1)
    const float* sh = (const float*)d_in[1];   // (64, 1, 64)
    float* out = (float*)d_out;                // (32, 8192, 64)

    shapelet_fused<<<32 * 32, 256, 0, stream>>>(x, sh, out);
}